// Round 5
// baseline (413.194 us; speedup 1.0000x reference)
//
#include <hip/hip_runtime.h>
#include <hip/hip_bf16.h>
#include <stdint.h>

// Causal MHA, B=8 S=2048 E=768 N=12 H=64. fp32 in/out, bf16 MFMA compute.
// prep -> QKV gemm (DIRECT register GEMM: no LDS, no barriers, 16B/lane
// fragment gathers straight from L1/L2) -> flash attention -> out gemm (same
// direct structure).

#define B_ 8
#define S_ 2048
#define E_ 768
#define NHEADS 12
#define HD 64
#define BS (B_*S_)        // 16384
#define NHD (NHEADS*HD)   // 768

typedef short bf16x8 __attribute__((ext_vector_type(8)));   // 8 bf16 = 4 VGPR
typedef short bf16x4 __attribute__((ext_vector_type(4)));
typedef float f32x4  __attribute__((ext_vector_type(4)));   // MFMA C/D frag
typedef __hip_bfloat16 bf16;

__device__ __forceinline__ f32x4 mfma16(bf16x8 a, bf16x8 b, f32x4 c) {
    return __builtin_amdgcn_mfma_f32_16x16x32_bf16(a, b, c, 0, 0, 0);
}
__device__ __forceinline__ bf16x8 ld8(const bf16* p) {
    return *reinterpret_cast<const bf16x8*>(p);
}
__device__ __forceinline__ bf16x8 pack8(f32x4 a, f32x4 b) {
    union { bf16x8 v; __hip_bfloat162 h[4]; } u;
    u.h[0] = __float22bfloat162_rn(make_float2(a[0], a[1]));
    u.h[1] = __float22bfloat162_rn(make_float2(a[2], a[3]));
    u.h[2] = __float22bfloat162_rn(make_float2(b[0], b[1]));
    u.h[3] = __float22bfloat162_rn(make_float2(b[2], b[3]));
    return u.v;
}

// ---------------- prep: fp32 -> bf16 casts + weight transposes ----------------
__global__ __launch_bounds__(256) void prep_kernel(
    const float* __restrict__ x,  const float* __restrict__ Wq,
    const float* __restrict__ Wk, const float* __restrict__ Wv,
    const float* __restrict__ Wo,
    bf16* __restrict__ xb,  bf16* __restrict__ WqT, bf16* __restrict__ WkT,
    bf16* __restrict__ WvT, bf16* __restrict__ WoT)
{
    const int tid = blockIdx.x * 256 + threadIdx.x;
    const int nth = gridDim.x * 256;
    for (int i = tid; i < BS*E_; i += nth)
        xb[i] = __float2bfloat16(x[i]);
    for (int i = tid; i < NHD*E_; i += nth) {
        const int c = i / E_;
        const int e = i - c*E_;
        const int n = c >> 6, h = c & 63;
        const int src = (n*E_ + e)*HD + h;       // W_[n][e][h]
        WqT[i] = __float2bfloat16(Wq[src]);
        WkT[i] = __float2bfloat16(Wk[src]);
        WvT[i] = __float2bfloat16(Wv[src]);
        WoT[e*NHD + c] = __float2bfloat16(Wo[i]); // Wo flat[c*E+e] = W_O[n][h][e]
    }
}

// ===================== direct register GEMM core (no LDS) ====================
// BM=128, BN=96, BK=64, 256 threads = 4 waves (wm=w>>1, wn=w&1), wave tile
// 64x48 -> acc[4][3]. Fragments are 16B/lane contiguous in global memory
// (row-major stride 768, B stored transposed), so each wave gathers its
// MFMA operands directly to VGPRs: per K-tile 8 A-loads + 6 B-loads + 24 MFMA.
// No LDS, no barriers, no explicit waitcnt: 12 independent waves/CU
// (launch_bounds(256,3)) desynchronize freely and the compiler pipelines the
// unrolled K-loop (all frag indices compile-time -> registers, rule 20).
// A-row reuse across quads (4 quads share each 64B row segment) and across
// the 2 waves with equal wm is served by L1; B panels are L2/L3-resident.

#define DIRECT_GEMM_BODY(Ath, Bth)                                                \
    f32x4 acc[4][3];                                                              \
    _Pragma("unroll") for (int mf = 0; mf < 4; ++mf)                              \
    _Pragma("unroll") for (int nf = 0; nf < 3; ++nf)                              \
        acc[mf][nf] = (f32x4){0.f, 0.f, 0.f, 0.f};                                \
    _Pragma("unroll")                                                             \
    for (int kt = 0; kt < 12; ++kt) {                                             \
        bf16x8 af[4][2], bf[3][2];                                                \
        _Pragma("unroll") for (int m = 0; m < 4; ++m)                             \
        _Pragma("unroll") for (int ks = 0; ks < 2; ++ks)                          \
            af[m][ks] = ld8((Ath) + (size_t)(m*16)*768 + kt*64 + ks*32);          \
        _Pragma("unroll") for (int n = 0; n < 3; ++n)                             \
        _Pragma("unroll") for (int ks = 0; ks < 2; ++ks)                          \
            bf[n][ks] = ld8((Bth) + (size_t)(n*16)*768 + kt*64 + ks*32);          \
        _Pragma("unroll") for (int ks = 0; ks < 2; ++ks)                          \
        _Pragma("unroll") for (int m = 0; m < 4; ++m)                             \
        _Pragma("unroll") for (int n = 0; n < 3; ++n)                             \
            acc[m][n] = mfma16(af[m][ks], bf[n][ks], acc[m][n]);                  \
    }

// ---------------- QKV projection GEMM (direct) ----------------
// WT = concatenated [WqT; WkT; WvT] = [2304][768]; tn 0..23 spans it (96 cols).
__global__ __launch_bounds__(256, 3) void qkv_gemm_d(
    const bf16* __restrict__ xb, const bf16* __restrict__ WT,
    const float* __restrict__ bq, const float* __restrict__ bk, const float* __restrict__ bv,
    bf16* __restrict__ Qb, bf16* __restrict__ Kb, bf16* __restrict__ VTb)
{
    const int tm = blockIdx.x, tn = blockIdx.y;
    const int lane = threadIdx.x & 63;
    const int w    = threadIdx.x >> 6;      // 0..3
    const int wm = w >> 1, wn = w & 1;
    const int l16 = lane & 15, quad = lane >> 4;
    const bf16* Ath = xb + (size_t)(tm*128 + wm*64 + l16)*768 + quad*8;
    const bf16* Bth = WT + (size_t)(tn*96  + wn*48 + l16)*768 + quad*8;

    DIRECT_GEMM_BODY(Ath, Bth);

    const int mat = tn >> 3;                 // 0=Q 1=K 2=V
    const int cloc0 = (tn & 7)*96 + wn*48;
    const float* bias = (mat==0) ? bq : (mat==1) ? bk : bv;
    const float scale = (mat==0) ? 0.125f * 1.44269504088896340736f : 1.0f;
    bf16* dstQK = (mat==0) ? Qb : Kb;
    #pragma unroll
    for (int nf = 0; nf < 3; ++nf) {
        const int col = cloc0 + nf*16 + l16;       // 0..767 within matrix
        const int hn = col >> 6, h = col & 63;
        const float bb = bias[col];
        #pragma unroll
        for (int mf = 0; mf < 4; ++mf) {
            const int row = tm*128 + wm*64 + mf*16 + quad*4;
            const int bi = row >> 11;              // / S_
            const int s  = row & (S_-1);
            if (mat < 2) {                         // Q,K -> [B][N][S][H]
                bf16* d = dstQK + ((size_t)(bi*NHEADS + hn)*S_ + s)*HD + h;
                #pragma unroll
                for (int r = 0; r < 4; ++r)
                    d[(size_t)r*HD] = __float2bfloat16((acc[mf][nf][r] + bb)*scale);
            } else {                               // V -> transposed [B][N][H][S]
                bf16* d = VTb + ((size_t)(bi*NHEADS + hn)*HD + h)*S_ + s;
                union { bf16x4 v; bf16 e[4]; } u;
                #pragma unroll
                for (int r = 0; r < 4; ++r) u.e[r] = __float2bfloat16(acc[mf][nf][r] + bb);
                *reinterpret_cast<bf16x4*>(d) = u.v;   // s%4==0 -> 8B aligned
            }
        }
    }
}

// ---------------- output projection (direct): out = Z @ Wo + bo --------------
__global__ __launch_bounds__(256, 3) void out_gemm_d(
    const bf16* __restrict__ Z, const bf16* __restrict__ WoT,
    const float* __restrict__ bo, float* __restrict__ out)
{
    const int tm = blockIdx.x, tn = blockIdx.y;
    const int lane = threadIdx.x & 63;
    const int w    = threadIdx.x >> 6;
    const int wm = w >> 1, wn = w & 1;
    const int l16 = lane & 15, quad = lane >> 4;
    const bf16* Ath = Z   + (size_t)(tm*128 + wm*64 + l16)*768 + quad*8;
    const bf16* Bth = WoT + (size_t)(tn*96  + wn*48 + l16)*768 + quad*8;

    DIRECT_GEMM_BODY(Ath, Bth);

    #pragma unroll
    for (int nf = 0; nf < 3; ++nf) {
        const int col = tn*96 + wn*48 + nf*16 + l16;
        const float bb = bo[col];
        #pragma unroll
        for (int mf = 0; mf < 4; ++mf) {
            const int row = tm*128 + wm*64 + mf*16 + quad*4;
            float* d = out + (size_t)row*E_ + col;
            #pragma unroll
            for (int r = 0; r < 4; ++r)
                d[(size_t)r*E_] = acc[mf][nf][r] + bb;
        }
    }
}

// ---------------- flash attention (LDS-staged K/V, double-buffered) -----------
__global__ __launch_bounds__(256, 3) void attn_kernel(
    const bf16* __restrict__ Qb, const bf16* __restrict__ Kb,
    const bf16* __restrict__ VTb, bf16* __restrict__ Z)
{
    __shared__ __align__(16) bf16 sK[2][64*64];
    __shared__ __align__(16) bf16 sV[2][64*64];

    const int id = blockIdx.x;
    const int bx = id / 96;                  // 0..7
    const int g  = id - bx*96;
    const int hn = g % NHEADS, b = g / NHEADS;
    const int tid  = threadIdx.x;
    const int w    = tid >> 6;
    const int lane = tid & 63;
    const int l16 = lane & 15, quad = lane >> 4;
    const size_t bn = (size_t)b*NHEADS + hn;

    const bf16* Qbase = Qb  + bn*S_*HD;
    const bf16* Kbase = Kb  + bn*S_*HD;
    const bf16* Vbase = VTb + bn*HD*S_;

    const int mA = tid, mB = tid + 256;
    const int rA = mA >> 3, cgA = mA & 7;
    const int rB = mB >> 3, cgB = mB & 7;
    const int slA = (rA*8 + ((cgA + rA + (rA>>3)) & 7)) * 8;
    const int slB = (rB*8 + ((cgB + rB + (rB>>3)) & 7)) * 8;
    const size_t vofA = (size_t)rA*S_ + cgA*8;
    const size_t vofB = (size_t)rB*S_ + cgB*8;

    const int kperm = (l16 >> 2)*8 + (l16 & 3);
    int kidx[2][2][2];
    #pragma unroll
    for (int c=0;c<2;c++)
        #pragma unroll
        for (int bg=0;bg<2;bg++)
            #pragma unroll
            for (int hf=0;hf<2;hf++) {
                const int r = 32*c + 4*bg + kperm;
                const int q = hf*4 + quad;
                kidx[c][bg][hf] = (r*8 + ((q + r + (r>>3)) & 7)) * 8;
            }
    int vidx[4][2];
    #pragma unroll
    for (int ht=0;ht<4;ht++)
        #pragma unroll
        for (int c=0;c<2;c++) {
            const int rho = ht*16 + l16;
            const int q = c*4 + quad;
            vidx[ht][c] = (rho*8 + ((q + rho + (rho>>3)) & 7)) * 8;
        }

    #pragma unroll
    for (int half = 0; half < 2; ++half) {
        const int qblk = half ? (S_/128 - 1 - bx) : bx;
        const int ktb  = 2*qblk + 1;
        const int ktw  = 2*qblk + (w >> 1);
        const int qbase = qblk*128 + w*32;

        bf16x8 bqf[2][2];
        #pragma unroll
        for (int qi=0;qi<2;qi++)
            #pragma unroll
            for (int hf=0;hf<2;hf++)
                bqf[qi][hf] = ld8(Qbase + (size_t)(qbase + qi*16 + l16)*HD + hf*32 + quad*8);

        f32x4 acc[2][4];
        #pragma unroll
        for (int qi=0;qi<2;qi++)
            #pragma unroll
            for (int ht=0;ht<4;ht++) acc[qi][ht] = (f32x4){0.f,0.f,0.f,0.f};
        float lsum[2] = {0.f, 0.f};

        bf16x8 k0 = ld8(Kbase + (size_t)mA*8);
        bf16x8 k1 = ld8(Kbase + (size_t)mB*8);
        bf16x8 v0 = ld8(Vbase + vofA);
        bf16x8 v1 = ld8(Vbase + vofB);
        *reinterpret_cast<bf16x8*>(&sK[0][slA]) = k0;
        *reinterpret_cast<bf16x8*>(&sK[0][slB]) = k1;
        *reinterpret_cast<bf16x8*>(&sV[0][slA]) = v0;
        *reinterpret_cast<bf16x8*>(&sV[0][slB]) = v1;
        __syncthreads();

        for (int kt = 0; kt <= ktb; ++kt) {
            if (kt < ktb) {
                const size_t kt1 = (size_t)(kt+1)*64;
                k0 = ld8(Kbase + kt1*HD + (size_t)mA*8);
                k1 = ld8(Kbase + kt1*HD + (size_t)mB*8);
                v0 = ld8(Vbase + vofA + kt1);
                v1 = ld8(Vbase + vofB + kt1);
            }
            if (kt <= ktw) {
                const bf16* kb = sK[kt & 1];
                const bf16* vb = sV[kt & 1];
                #pragma unroll
                for (int c=0;c<2;c++) {
                    const bf16x8 akA0 = ld8(kb + kidx[c][0][0]);
                    const bf16x8 akA1 = ld8(kb + kidx[c][0][1]);
                    const bf16x8 akB0 = ld8(kb + kidx[c][1][0]);
                    const bf16x8 akB1 = ld8(kb + kidx[c][1][1]);
                    bf16x8 av[4];
                    #pragma unroll
                    for (int ht=0;ht<4;ht++) av[ht] = ld8(vb + vidx[ht][c]);

                    #pragma unroll
                    for (int qi=0;qi<2;qi++) {
                        f32x4 s0 = (f32x4){0.f,0.f,0.f,0.f};
                        s0 = mfma16(akA0, bqf[qi][0], s0);
                        s0 = mfma16(akA1, bqf[qi][1], s0);
                        f32x4 s1 = (f32x4){0.f,0.f,0.f,0.f};
                        s1 = mfma16(akB0, bqf[qi][0], s1);
                        s1 = mfma16(akB1, bqf[qi][1], s1);
                        if (kt == ktw) {
                            const int q  = qbase + qi*16 + l16;
                            const int kb0 = kt*64 + c*32 + quad*8;
                            #pragma unroll
                            for (int r=0;r<4;r++) {
                                s0[r] = (kb0 + r     > q) ? -1e30f : s0[r];
                                s1[r] = (kb0 + 4 + r > q) ? -1e30f : s1[r];
                            }
                        }
                        float ls = 0.f;
                        #pragma unroll
                        for (int r=0;r<4;r++) {
                            s0[r] = __builtin_amdgcn_exp2f(s0[r]);
                            s1[r] = __builtin_amdgcn_exp2f(s1[r]);
                            ls += s0[r] + s1[r];
                        }
                        lsum[qi] += ls;
                        const bf16x8 pf = pack8(s0, s1);
                        #pragma unroll
                        for (int ht=0;ht<4;ht++)
                            acc[qi][ht] = mfma16(av[ht], pf, acc[qi][ht]);
                    }
                }
            }
            if (kt < ktb) {
                const int nb = (kt+1) & 1;
                *reinterpret_cast<bf16x8*>(&sK[nb][slA]) = k0;
                *reinterpret_cast<bf16x8*>(&sK[nb][slB]) = k1;
                *reinterpret_cast<bf16x8*>(&sV[nb][slA]) = v0;
                *reinterpret_cast<bf16x8*>(&sV[nb][slB]) = v1;
            }
            __syncthreads();
        }

        #pragma unroll
        for (int qi=0;qi<2;qi++) {
            float rs = lsum[qi];
            rs += __shfl_xor(rs, 16, 64);
            rs += __shfl_xor(rs, 32, 64);
            const float inv_l = 1.0f / rs;
            const int q = qbase + qi*16 + l16;
            bf16* zp = Z + ((size_t)b*S_ + q)*NHD + (size_t)hn*HD + quad*4;
            #pragma unroll
            for (int ht=0;ht<4;ht++) {
                union { bf16x4 v; bf16 e[4]; } u;
                #pragma unroll
                for (int r=0;r<4;r++) u.e[r] = __float2bfloat16(acc[qi][ht][r] * inv_l);
                *reinterpret_cast<bf16x4*>(zp + ht*16) = u.v;
            }
        }
    }
}

extern "C" void kernel_launch(void* const* d_in, const int* in_sizes, int n_in,
                              void* d_out, int out_size, void* d_ws, size_t ws_size,
                              hipStream_t stream)
{
    const float* x  = (const float*)d_in[0];
    const float* Wq = (const float*)d_in[1];
    const float* Wk = (const float*)d_in[2];
    const float* Wv = (const float*)d_in[3];
    const float* Wo = (const float*)d_in[4];
    const float* bq = (const float*)d_in[5];
    const float* bk = (const float*)d_in[6];
    const float* bv = (const float*)d_in[7];
    const float* bo = (const float*)d_in[8];
    float* out = (float*)d_out;

    char* ws = (char*)d_ws;
    size_t off = 0;
    auto alloc = [&](size_t bytes){ char* p = ws + off; off += (bytes + 255) & ~(size_t)255; return p; };
    bf16* xb  = (bf16*)alloc((size_t)BS*E_*2);
    bf16* WT  = (bf16*)alloc((size_t)3*NHD*E_*2);  // [WqT; WkT; WvT] = [2304][768]
    bf16* WoT = (bf16*)alloc((size_t)E_*NHD*2);
    bf16* Qb  = (bf16*)alloc((size_t)BS*NHD*2);   // [B][N][S][H], pre-scaled log2e/8
    bf16* Kb  = (bf16*)alloc((size_t)BS*NHD*2);   // [B][N][S][H]
    bf16* VTb = (bf16*)alloc((size_t)BS*NHD*2);   // [B][N][H][S]
    bf16* Zb  = (bf16*)alloc((size_t)BS*NHD*2);   // [BS][NHD]

    bf16* WqT = WT;
    bf16* WkT = WT + (size_t)NHD*E_;
    bf16* WvT = WT + (size_t)2*NHD*E_;

    prep_kernel<<<4096, 256, 0, stream>>>(x, Wq, Wk, Wv, Wo, xb, WqT, WkT, WvT, WoT);
    qkv_gemm_d<<<dim3(BS/128, 24), 256, 0, stream>>>(xb, WT, bq, bk, bv, Qb, Kb, VTb);
    attn_kernel<<<768, 256, 0, stream>>>(Qb, Kb, VTb, Zb);
    out_gemm_d<<<dim3(BS/128, 8), 256, 0, stream>>>(Zb, WoT, bo, out);
}

// Round 6
// 258.248 us; speedup vs baseline: 1.6000x; 1.6000x over previous
//
#include <hip/hip_runtime.h>
#include <hip/hip_bf16.h>
#include <stdint.h>

// Causal MHA, B=8 S=2048 E=768 N=12 H=64. fp32 in/out, bf16 MFMA compute.
// prep packs x and W_QKV into FRAGMENT-MAJOR layout -> qkv gemm reads MFMA
// operands as contiguous 1KB wave-loads straight from L1/L2 (no LDS, no
// barriers, full TLP) -> flash attention (unchanged) -> out gemm (R3 staged
// 256x192 structure, unchanged).

#define B_ 8
#define S_ 2048
#define E_ 768
#define NHEADS 12
#define HD 64
#define BS (B_*S_)        // 16384
#define NHD (NHEADS*HD)   // 768

typedef short bf16x8 __attribute__((ext_vector_type(8)));   // 8 bf16 = 4 VGPR
typedef short bf16x4 __attribute__((ext_vector_type(4)));
typedef float f32x4  __attribute__((ext_vector_type(4)));   // MFMA C/D frag
typedef __hip_bfloat16 bf16;

typedef const __attribute__((address_space(1))) char* as1_t;
typedef __attribute__((address_space(3))) char* as3_t;

__device__ __forceinline__ f32x4 mfma16(bf16x8 a, bf16x8 b, f32x4 c) {
    return __builtin_amdgcn_mfma_f32_16x16x32_bf16(a, b, c, 0, 0, 0);
}
__device__ __forceinline__ bf16x8 ld8(const bf16* p) {
    return *reinterpret_cast<const bf16x8*>(p);
}
// async global->LDS, 16B/lane; lds dest = wave-uniform base + lane*16
__device__ __forceinline__ void gload16(const bf16* g, bf16* l) {
    __builtin_amdgcn_global_load_lds((as1_t)g, (as3_t)l, 16, 0, 0);
}
__device__ __forceinline__ bf16x8 pack8(f32x4 a, f32x4 b) {
    union { bf16x8 v; __hip_bfloat162 h[4]; } u;
    u.h[0] = __float22bfloat162_rn(make_float2(a[0], a[1]));
    u.h[1] = __float22bfloat162_rn(make_float2(a[2], a[3]));
    u.h[2] = __float22bfloat162_rn(make_float2(b[0], b[1]));
    u.h[3] = __float22bfloat162_rn(make_float2(b[2], b[3]));
    return u.v;
}

// Fragment-major packed layout for an [R][768] row-major matrix:
// frag (rg = r/16, kc = k/32) occupies 512 elems at ((rg*24)+kc)*512;
// within a frag, element (rl=r%16, kq=(k%32)/8, e=k%8) sits at
// (kq*16 + rl)*8 + e  == lane ℓ = kq*16+rl reads its 8 elems at ℓ*8.
// This is exactly the MFMA A/B fragment order: one ld8 at base+lane*8
// yields the 16x16x32 operand for row-group rg, k-chunk kc.

// ---------------- prep: pack x and W_QKV fragment-major; WoT row-major -------
__global__ __launch_bounds__(256) void prep_kernel(
    const float* __restrict__ x,  const float* __restrict__ Wq,
    const float* __restrict__ Wk, const float* __restrict__ Wv,
    const float* __restrict__ Wo,
    bf16* __restrict__ xp,  bf16* __restrict__ WTp, bf16* __restrict__ WoT)
{
    const int tid = blockIdx.x * 256 + threadIdx.x;
    const int nth = gridDim.x * 256;

    // x [16384][768] f32 -> packed bf16 (coalesced f32 reads, 16B writes)
    for (int c = tid; c < BS*E_/8; c += nth) {
        const int r  = c / 96;               // row
        const int k8 = (c - r*96) * 8;       // k start (multiple of 8)
        const float4 f0 = *reinterpret_cast<const float4*>(x + (size_t)r*E_ + k8);
        const float4 f1 = *reinterpret_cast<const float4*>(x + (size_t)r*E_ + k8 + 4);
        union { bf16x8 v; __hip_bfloat162 h[4]; } u;
        u.h[0] = __float22bfloat162_rn(make_float2(f0.x, f0.y));
        u.h[1] = __float22bfloat162_rn(make_float2(f0.z, f0.w));
        u.h[2] = __float22bfloat162_rn(make_float2(f1.x, f1.y));
        u.h[3] = __float22bfloat162_rn(make_float2(f1.z, f1.w));
        const size_t dst = (size_t)((r>>4)*24 + (k8>>5))*512
                         + (size_t)((((k8>>3)&3)<<4) + (r&15))*8;
        *reinterpret_cast<bf16x8*>(xp + dst) = u.v;
    }

    // W_{Q,K,V}[n][e][h] -> packed B rows r = mat*768 + (n*64+h), k = e
    for (int c2 = tid; c2 < NHD*96; c2 += nth) {
        const int r  = c2 / 96;              // (n,h) output-col index 0..767
        const int e8 = (c2 - r*96) * 8;      // k start
        const int n = r >> 6, h = r & 63;
        const float* sq = Wq + (size_t)(n*E_ + e8)*HD + h;
        const float* sk = Wk + (size_t)(n*E_ + e8)*HD + h;
        const float* sv = Wv + (size_t)(n*E_ + e8)*HD + h;
        union { bf16x8 v; bf16 el[8]; } uq, uk, uv;
        #pragma unroll
        for (int j = 0; j < 8; ++j) {
            uq.el[j] = __float2bfloat16(sq[(size_t)j*HD]);
            uk.el[j] = __float2bfloat16(sk[(size_t)j*HD]);
            uv.el[j] = __float2bfloat16(sv[(size_t)j*HD]);
        }
        const size_t sub = (size_t)(e8>>5)*512
                         + (size_t)((((e8>>3)&3)<<4) + (r&15))*8;
        const size_t rg  = (size_t)(r>>4);   // within-matrix row-group
        *reinterpret_cast<bf16x8*>(WTp + ((0*48 + rg)*24)*512 + sub) = uq.v;
        *reinterpret_cast<bf16x8*>(WTp + ((1*48 + rg)*24)*512 + sub) = uk.v;
        *reinterpret_cast<bf16x8*>(WTp + ((2*48 + rg)*24)*512 + sub) = uv.v;
    }

    // Wo flat[c][e] -> WoT[e][c] (row-major, for the staged out_gemm)
    for (int i = tid; i < NHD*E_; i += nth) {
        const int cc = i / E_;
        const int e  = i - cc*E_;
        WoT[(size_t)e*NHD + cc] = __float2bfloat16(Wo[i]);
    }
}

// ============ QKV projection: direct packed-fragment GEMM (no LDS) ===========
// BM=128, BN=96, 256 threads = 4 waves (wm=w>>1, wn=w&1), wave tile 64x48.
// Per K-tile: 8 A-loads + 6 B-loads, each ONE contiguous 1KB wave-load from
// the packed layout (base + lane*16B), then 24 MFMA. No barriers anywhere:
// 3 blocks/CU (launch_bounds(256,3)) give 12 free-running waves/CU; the
// compiler software-pipelines the fully unrolled K-loop (all indices static).
// Intra-block reuse: the 2 wn-waves share A-frags, the 2 wm-waves share
// B-frags -> L1 serves ~half the demand.
__global__ __launch_bounds__(256, 3) void qkv_gemm_p(
    const bf16* __restrict__ xp, const bf16* __restrict__ WTp,
    const float* __restrict__ bq, const float* __restrict__ bk, const float* __restrict__ bv,
    bf16* __restrict__ Qb, bf16* __restrict__ Kb, bf16* __restrict__ VTb)
{
    const int tm = blockIdx.x, tn = blockIdx.y;   // (128, 24)
    const int lane = threadIdx.x & 63;
    const int w    = threadIdx.x >> 6;            // 0..3
    const int wm = w >> 1, wn = w & 1;
    const int l16 = lane & 15, quad = lane >> 4;
    const bf16* Abase = xp  + (size_t)(tm*8 + wm*4)*24*512 + lane*8;
    const bf16* Bbase = WTp + (size_t)(tn*6 + wn*3)*24*512 + lane*8;

    f32x4 acc[4][3];
    #pragma unroll
    for (int mf = 0; mf < 4; ++mf)
        #pragma unroll
        for (int nf = 0; nf < 3; ++nf)
            acc[mf][nf] = (f32x4){0.f, 0.f, 0.f, 0.f};

    #pragma unroll
    for (int kt = 0; kt < 12; ++kt) {
        bf16x8 af[4][2], bfr[3][2];
        #pragma unroll
        for (int m = 0; m < 2; ++m)
            #pragma unroll
            for (int ks = 0; ks < 2; ++ks)
                af[m][ks] = ld8(Abase + ((size_t)m*24 + kt*2 + ks)*512);
        #pragma unroll
        for (int n = 0; n < 3; ++n)
            #pragma unroll
            for (int ks = 0; ks < 2; ++ks)
                bfr[n][ks] = ld8(Bbase + ((size_t)n*24 + kt*2 + ks)*512);
        #pragma unroll
        for (int m = 2; m < 4; ++m)
            #pragma unroll
            for (int ks = 0; ks < 2; ++ks)
                af[m][ks] = ld8(Abase + ((size_t)m*24 + kt*2 + ks)*512);
        #pragma unroll
        for (int ks = 0; ks < 2; ++ks)
            #pragma unroll
            for (int m = 0; m < 4; ++m)
                #pragma unroll
                for (int n = 0; n < 3; ++n)
                    acc[m][n] = mfma16(af[m][ks], bfr[n][ks], acc[m][n]);
    }

    const int mat = tn >> 3;                 // 0=Q 1=K 2=V
    const int cloc0 = (tn & 7)*96 + wn*48;
    const float* bias = (mat==0) ? bq : (mat==1) ? bk : bv;
    const float scale = (mat==0) ? 0.125f * 1.44269504088896340736f : 1.0f;
    bf16* dstQK = (mat==0) ? Qb : Kb;
    #pragma unroll
    for (int nf = 0; nf < 3; ++nf) {
        const int col = cloc0 + nf*16 + l16;       // 0..767 within matrix
        const int hn = col >> 6, h = col & 63;
        const float bb = bias[col];
        #pragma unroll
        for (int mf = 0; mf < 4; ++mf) {
            const int row = tm*128 + wm*64 + mf*16 + quad*4;
            const int bi = row >> 11;              // / S_
            const int s  = row & (S_-1);
            if (mat < 2) {                         // Q,K -> [B][N][S][H]
                bf16* d = dstQK + ((size_t)(bi*NHEADS + hn)*S_ + s)*HD + h;
                #pragma unroll
                for (int r = 0; r < 4; ++r)
                    d[(size_t)r*HD] = __float2bfloat16((acc[mf][nf][r] + bb)*scale);
            } else {                               // V -> transposed [B][N][H][S]
                bf16* d = VTb + ((size_t)(bi*NHEADS + hn)*HD + h)*S_ + s;
                union { bf16x4 v; bf16 e[4]; } u;
                #pragma unroll
                for (int r = 0; r < 4; ++r) u.e[r] = __float2bfloat16(acc[mf][nf][r] + bb);
                *reinterpret_cast<bf16x4*>(d) = u.v;   // s%4==0 -> 8B aligned
            }
        }
    }
}

// ======================= 256x192 8-phase GEMM core (R3) ======================
// Kept for out_gemm only. Triple-buffered A, double-buffered B, vmcnt(7).
#define FENCE() asm volatile("" ::: "memory")
#define VMCNT7() asm volatile("s_waitcnt vmcnt(7)" ::: "memory")
#define MIN11(x) ((x) < 11 ? (x) : 11)

#define A_ELEM(kh, rg) (((kh)*16 + (rg))*512)
#define B_ELEM(kh, rg) (((kh)*12 + (rg))*512)

#define STG_A(dst, gbase, kt, kh) do {                                            \
    const bf16* _s = (gbase) + (size_t)(l16)*768 + (kt)*64 + (kh)*32 + quad*8;    \
    gload16(_s + (size_t)(w*16)*768,     &(dst)[A_ELEM(kh, w)]);                  \
    gload16(_s + (size_t)((w+8)*16)*768, &(dst)[A_ELEM(kh, w+8)]);                \
} while (0)

#define STG_B(dst, gbase, kt) do {                                                \
    const bf16* _s = (gbase) + (size_t)(l16)*768 + (kt)*64 + quad*8;              \
    const int _k1 = (w < 4) ? 0 : 1;                                              \
    const int _r1 = (w < 4) ? (w + 8) : (w - 4);                                  \
    gload16(_s + (size_t)(w*16)*768,        &(dst)[B_ELEM(0, w)]);                \
    gload16(_s + (size_t)(_r1*16)*768 + _k1*32, &(dst)[B_ELEM(_k1, _r1)]);        \
    gload16(_s + (size_t)((w+4)*16)*768 + 32,   &(dst)[B_ELEM(1, w+4)]);          \
} while (0)

#define PHASE(bufA, bufB, q, LOADB, STAGE, WAIT) do {                             \
    if (LOADB) {                                                                  \
        _Pragma("unroll") for (int n = 0; n < 3; ++n)                             \
        _Pragma("unroll") for (int ks = 0; ks < 2; ++ks)                          \
            bfr[n][ks] = ld8(&(bufB)[((ks)*12 + wn*3 + n)*512 + lane*8]);         \
    }                                                                             \
    bf16x8 afr[2][2];                                                             \
    _Pragma("unroll") for (int m = 0; m < 2; ++m)                                 \
    _Pragma("unroll") for (int ks = 0; ks < 2; ++ks)                              \
        afr[m][ks] = ld8(&(bufA)[((ks)*16 + wm*8 + (q)*2 + m)*512 + lane*8]);     \
    STAGE;                                                                        \
    FENCE(); __builtin_amdgcn_s_barrier(); FENCE();                               \
    asm volatile("s_waitcnt lgkmcnt(0)" ::: "memory");                            \
    __builtin_amdgcn_s_setprio(1);                                                \
    _Pragma("unroll") for (int m = 0; m < 2; ++m)                                 \
    _Pragma("unroll") for (int n = 0; n < 3; ++n)                                 \
    _Pragma("unroll") for (int ks = 0; ks < 2; ++ks)                              \
        acc[(q)*2 + m][n] = mfma16(afr[m][ks], bfr[n][ks], acc[(q)*2 + m][n]);    \
    __builtin_amdgcn_s_setprio(0);                                                \
    WAIT;                                                                         \
    FENCE(); __builtin_amdgcn_s_barrier(); FENCE();                               \
} while (0)

#define ITER8(r0, r1, w2, k0, Ab, Bb)                                             \
    PHASE(r0, sB0, 0, 1, STG_A(w2, Ab, MIN11((k0)+2), 0), (void)0);               \
    PHASE(r0, sB0, 1, 0, STG_A(w2, Ab, MIN11((k0)+2), 1), (void)0);               \
    PHASE(r0, sB0, 2, 0, STG_B(sB0, Bb, MIN11((k0)+2)),   (void)0);               \
    PHASE(r0, sB0, 3, 0, (void)0,                         VMCNT7());              \
    PHASE(r1, sB1, 0, 1, STG_A(r0, Ab, MIN11((k0)+3), 0), (void)0);               \
    PHASE(r1, sB1, 1, 0, STG_A(r0, Ab, MIN11((k0)+3), 1), (void)0);               \
    PHASE(r1, sB1, 2, 0, STG_B(sB1, Bb, MIN11((k0)+3)),   (void)0);               \
    PHASE(r1, sB1, 3, 0, (void)0,                         VMCNT7());

#define GEMM192_BODY(Ab, Bb)                                                      \
    f32x4 acc[8][3];                                                              \
    _Pragma("unroll") for (int mf = 0; mf < 8; ++mf)                              \
    _Pragma("unroll") for (int nf = 0; nf < 3; ++nf)                              \
        acc[mf][nf] = (f32x4){0.f, 0.f, 0.f, 0.f};                                \
    bf16x8 bfr[3][2];                                                             \
    STG_A(sA0, Ab, 0, 0); STG_A(sA0, Ab, 0, 1);                                   \
    STG_B(sB0, Bb, 0);                                                            \
    STG_A(sA1, Ab, 1, 0); STG_A(sA1, Ab, 1, 1);                                   \
    STG_B(sB1, Bb, 1);                                                            \
    VMCNT7();                                                                     \
    FENCE(); __builtin_amdgcn_s_barrier(); FENCE();                               \
    _Pragma("unroll 1")                                                           \
    for (int ii = 0; ii < 2; ++ii) {                                              \
        const int k0 = 6*ii;                                                      \
        ITER8(sA0, sA1, sA2, k0+0, Ab, Bb)                                        \
        ITER8(sA2, sA0, sA1, k0+2, Ab, Bb)                                        \
        ITER8(sA1, sA2, sA0, k0+4, Ab, Bb)                                        \
    }                                                                             \
    asm volatile("s_waitcnt vmcnt(0)" ::: "memory");

// ---------------- output projection (256x192 8-phase): out = Z @ Wo + bo -----
__global__ __launch_bounds__(512, 2) void out_gemm256(
    const bf16* __restrict__ Z, const bf16* __restrict__ WoT,
    const float* __restrict__ bo, float* __restrict__ out)
{
    __shared__ __align__(16) bf16 sA0[16384];
    __shared__ __align__(16) bf16 sA1[16384];
    __shared__ __align__(16) bf16 sA2[16384];
    __shared__ __align__(16) bf16 sB0[12288];
    __shared__ __align__(16) bf16 sB1[12288];

    const int tm = blockIdx.x, tn = blockIdx.y;
    const int lane = threadIdx.x & 63;
    const int w    = threadIdx.x >> 6;
    const int wm = w >> 2, wn = w & 3;
    const int l16 = lane & 15, quad = lane >> 4;
    const bf16* Ab = Z   + (size_t)tm*256*NHD;
    const bf16* Bb = WoT + (size_t)tn*192*NHD;

    GEMM192_BODY(Ab, Bb);

    #pragma unroll
    for (int nf = 0; nf < 3; ++nf) {
        const int col = tn*192 + wn*48 + nf*16 + l16;
        const float bb = bo[col];
        #pragma unroll
        for (int mf = 0; mf < 8; ++mf) {
            const int row = tm*256 + wm*128 + mf*16 + quad*4;
            float* d = out + (size_t)row*E_ + col;
            #pragma unroll
            for (int r = 0; r < 4; ++r)
                d[(size_t)r*E_] = acc[mf][nf][r] + bb;
        }
    }
}

// ---------------- flash attention (LDS-staged K/V, double-buffered) -----------
__global__ __launch_bounds__(256, 3) void attn_kernel(
    const bf16* __restrict__ Qb, const bf16* __restrict__ Kb,
    const bf16* __restrict__ VTb, bf16* __restrict__ Z)
{
    __shared__ __align__(16) bf16 sK[2][64*64];
    __shared__ __align__(16) bf16 sV[2][64*64];

    const int id = blockIdx.x;
    const int bx = id / 96;                  // 0..7
    const int g  = id - bx*96;
    const int hn = g % NHEADS, b = g / NHEADS;
    const int tid  = threadIdx.x;
    const int w    = tid >> 6;
    const int lane = tid & 63;
    const int l16 = lane & 15, quad = lane >> 4;
    const size_t bn = (size_t)b*NHEADS + hn;

    const bf16* Qbase = Qb  + bn*S_*HD;
    const bf16* Kbase = Kb  + bn*S_*HD;
    const bf16* Vbase = VTb + bn*HD*S_;

    const int mA = tid, mB = tid + 256;
    const int rA = mA >> 3, cgA = mA & 7;
    const int rB = mB >> 3, cgB = mB & 7;
    const int slA = (rA*8 + ((cgA + rA + (rA>>3)) & 7)) * 8;
    const int slB = (rB*8 + ((cgB + rB + (rB>>3)) & 7)) * 8;
    const size_t vofA = (size_t)rA*S_ + cgA*8;
    const size_t vofB = (size_t)rB*S_ + cgB*8;

    const int kperm = (l16 >> 2)*8 + (l16 & 3);
    int kidx[2][2][2];
    #pragma unroll
    for (int c=0;c<2;c++)
        #pragma unroll
        for (int bg=0;bg<2;bg++)
            #pragma unroll
            for (int hf=0;hf<2;hf++) {
                const int r = 32*c + 4*bg + kperm;
                const int q = hf*4 + quad;
                kidx[c][bg][hf] = (r*8 + ((q + r + (r>>3)) & 7)) * 8;
            }
    int vidx[4][2];
    #pragma unroll
    for (int ht=0;ht<4;ht++)
        #pragma unroll
        for (int c=0;c<2;c++) {
            const int rho = ht*16 + l16;
            const int q = c*4 + quad;
            vidx[ht][c] = (rho*8 + ((q + rho + (rho>>3)) & 7)) * 8;
        }

    #pragma unroll
    for (int half = 0; half < 2; ++half) {
        const int qblk = half ? (S_/128 - 1 - bx) : bx;
        const int ktb  = 2*qblk + 1;
        const int ktw  = 2*qblk + (w >> 1);
        const int qbase = qblk*128 + w*32;

        bf16x8 bqf[2][2];
        #pragma unroll
        for (int qi=0;qi<2;qi++)
            #pragma unroll
            for (int hf=0;hf<2;hf++)
                bqf[qi][hf] = ld8(Qbase + (size_t)(qbase + qi*16 + l16)*HD + hf*32 + quad*8);

        f32x4 acc[2][4];
        #pragma unroll
        for (int qi=0;qi<2;qi++)
            #pragma unroll
            for (int ht=0;ht<4;ht++) acc[qi][ht] = (f32x4){0.f,0.f,0.f,0.f};
        float lsum[2] = {0.f, 0.f};

        bf16x8 k0 = ld8(Kbase + (size_t)mA*8);
        bf16x8 k1 = ld8(Kbase + (size_t)mB*8);
        bf16x8 v0 = ld8(Vbase + vofA);
        bf16x8 v1 = ld8(Vbase + vofB);
        *reinterpret_cast<bf16x8*>(&sK[0][slA]) = k0;
        *reinterpret_cast<bf16x8*>(&sK[0][slB]) = k1;
        *reinterpret_cast<bf16x8*>(&sV[0][slA]) = v0;
        *reinterpret_cast<bf16x8*>(&sV[0][slB]) = v1;
        __syncthreads();

        for (int kt = 0; kt <= ktb; ++kt) {
            if (kt < ktb) {
                const size_t kt1 = (size_t)(kt+1)*64;
                k0 = ld8(Kbase + kt1*HD + (size_t)mA*8);
                k1 = ld8(Kbase + kt1*HD + (size_t)mB*8);
                v0 = ld8(Vbase + vofA + kt1);
                v1 = ld8(Vbase + vofB + kt1);
            }
            if (kt <= ktw) {
                const bf16* kb = sK[kt & 1];
                const bf16* vb = sV[kt & 1];
                #pragma unroll
                for (int c=0;c<2;c++) {
                    const bf16x8 akA0 = ld8(kb + kidx[c][0][0]);
                    const bf16x8 akA1 = ld8(kb + kidx[c][0][1]);
                    const bf16x8 akB0 = ld8(kb + kidx[c][1][0]);
                    const bf16x8 akB1 = ld8(kb + kidx[c][1][1]);
                    bf16x8 av[4];
                    #pragma unroll
                    for (int ht=0;ht<4;ht++) av[ht] = ld8(vb + vidx[ht][c]);

                    #pragma unroll
                    for (int qi=0;qi<2;qi++) {
                        f32x4 s0 = (f32x4){0.f,0.f,0.f,0.f};
                        s0 = mfma16(akA0, bqf[qi][0], s0);
                        s0 = mfma16(akA1, bqf[qi][1], s0);
                        f32x4 s1 = (f32x4){0.f,0.f,0.f,0.f};
                        s1 = mfma16(akB0, bqf[qi][0], s1);
                        s1 = mfma16(akB1, bqf[qi][1], s1);
                        if (kt == ktw) {
                            const int q  = qbase + qi*16 + l16;
                            const int kb0 = kt*64 + c*32 + quad*8;
                            #pragma unroll
                            for (int r=0;r<4;r++) {
                                s0[r] = (kb0 + r     > q) ? -1e30f : s0[r];
                                s1[r] = (kb0 + 4 + r > q) ? -1e30f : s1[r];
                            }
                        }
                        float ls = 0.f;
                        #pragma unroll
                        for (int r=0;r<4;r++) {
                            s0[r] = __builtin_amdgcn_exp2f(s0[r]);
                            s1[r] = __builtin_amdgcn_exp2f(s1[r]);
                            ls += s0[r] + s1[r];
                        }
                        lsum[qi] += ls;
                        const bf16x8 pf = pack8(s0, s1);
                        #pragma unroll
                        for (int ht=0;ht<4;ht++)
                            acc[qi][ht] = mfma16(av[ht], pf, acc[qi][ht]);
                    }
                }
            }
            if (kt < ktb) {
                const int nb = (kt+1) & 1;
                *reinterpret_cast<bf16x8*>(&sK[nb][slA]) = k0;
                *reinterpret_cast<bf16x8*>(&sK[nb][slB]) = k1;
                *reinterpret_cast<bf16x8*>(&sV[nb][slA]) = v0;
                *reinterpret_cast<bf16x8*>(&sV[nb][slB]) = v1;
            }
            __syncthreads();
        }

        #pragma unroll
        for (int qi=0;qi<2;qi++) {
            float rs = lsum[qi];
            rs += __shfl_xor(rs, 16, 64);
            rs += __shfl_xor(rs, 32, 64);
            const float inv_l = 1.0f / rs;
            const int q = qbase + qi*16 + l16;
            bf16* zp = Z + ((size_t)b*S_ + q)*NHD + (size_t)hn*HD + quad*4;
            #pragma unroll
            for (int ht=0;ht<4;ht++) {
                union { bf16x4 v; bf16 e[4]; } u;
                #pragma unroll
                for (int r=0;r<4;r++) u.e[r] = __float2bfloat16(acc[qi][ht][r] * inv_l);
                *reinterpret_cast<bf16x4*>(zp + ht*16) = u.v;
            }
        }
    }
}

extern "C" void kernel_launch(void* const* d_in, const int* in_sizes, int n_in,
                              void* d_out, int out_size, void* d_ws, size_t ws_size,
                              hipStream_t stream)
{
    const float* x  = (const float*)d_in[0];
    const float* Wq = (const float*)d_in[1];
    const float* Wk = (const float*)d_in[2];
    const float* Wv = (const float*)d_in[3];
    const float* Wo = (const float*)d_in[4];
    const float* bq = (const float*)d_in[5];
    const float* bk = (const float*)d_in[6];
    const float* bv = (const float*)d_in[7];
    const float* bo = (const float*)d_in[8];
    float* out = (float*)d_out;

    char* ws = (char*)d_ws;
    size_t off = 0;
    auto alloc = [&](size_t bytes){ char* p = ws + off; off += (bytes + 255) & ~(size_t)255; return p; };
    bf16* xp  = (bf16*)alloc((size_t)BS*E_*2);     // packed fragment-major
    bf16* WTp = (bf16*)alloc((size_t)3*NHD*E_*2);  // packed [Wq;Wk;Wv] B-frags
    bf16* WoT = (bf16*)alloc((size_t)E_*NHD*2);    // row-major (staged out gemm)
    bf16* Qb  = (bf16*)alloc((size_t)BS*NHD*2);    // [B][N][S][H], pre-scaled log2e/8
    bf16* Kb  = (bf16*)alloc((size_t)BS*NHD*2);    // [B][N][S][H]
    bf16* VTb = (bf16*)alloc((size_t)BS*NHD*2);    // [B][N][H][S]
    bf16* Zb  = (bf16*)alloc((size_t)BS*NHD*2);    // [BS][NHD]

    prep_kernel<<<4096, 256, 0, stream>>>(x, Wq, Wk, Wv, Wo, xp, WTp, WoT);
    qkv_gemm_p<<<dim3(BS/128, 24), 256, 0, stream>>>(xp, WTp, bq, bk, bv, Qb, Kb, VTb);
    attn_kernel<<<768, 256, 0, stream>>>(Qb, Kb, VTb, Zb);
    out_gemm256<<<dim3(BS/256, E_/192), 512, 0, stream>>>(Zb, WoT, bo, out);
}

// Round 7
// 234.238 us; speedup vs baseline: 1.7640x; 1.1025x over previous
//
#include <hip/hip_runtime.h>
#include <hip/hip_bf16.h>
#include <stdint.h>

// Causal MHA, B=8 S=2048 E=768 N=12 H=64. fp32 in/out, bf16 MFMA compute.
// prep packs x, W_QKV, W_O into FRAGMENT-MAJOR layout -> qkv gemm and out gemm
// are barrier-free direct register GEMMs with an explicit 2-deep per-wave
// prefetch pipeline (counted vmcnt via structure + sched_barrier pinning).
// attn writes Z directly in fragment-major so out_gemm needs no repack.

#define B_ 8
#define S_ 2048
#define E_ 768
#define NHEADS 12
#define HD 64
#define BS (B_*S_)        // 16384
#define NHD (NHEADS*HD)   // 768

typedef short bf16x8 __attribute__((ext_vector_type(8)));   // 8 bf16 = 4 VGPR
typedef short bf16x4 __attribute__((ext_vector_type(4)));
typedef float f32x4  __attribute__((ext_vector_type(4)));   // MFMA C/D frag
typedef __hip_bfloat16 bf16;

__device__ __forceinline__ f32x4 mfma16(bf16x8 a, bf16x8 b, f32x4 c) {
    return __builtin_amdgcn_mfma_f32_16x16x32_bf16(a, b, c, 0, 0, 0);
}
__device__ __forceinline__ bf16x8 ld8(const bf16* p) {
    return *reinterpret_cast<const bf16x8*>(p);
}
__device__ __forceinline__ bf16x8 pack8(f32x4 a, f32x4 b) {
    union { bf16x8 v; __hip_bfloat162 h[4]; } u;
    u.h[0] = __float22bfloat162_rn(make_float2(a[0], a[1]));
    u.h[1] = __float22bfloat162_rn(make_float2(a[2], a[3]));
    u.h[2] = __float22bfloat162_rn(make_float2(b[0], b[1]));
    u.h[3] = __float22bfloat162_rn(make_float2(b[2], b[3]));
    return u.v;
}

// Fragment-major packed layout for an [R][768] row-major matrix:
// frag (rg = r/16, kc = k/32) occupies 512 elems at (rg*24 + kc)*512;
// element (rl=r%16, kq=(k%32)/8, e=k%8) sits at (kq*16 + rl)*8 + e.
// One ld8 at frag_base + lane*8 is exactly the 16x16x32 MFMA operand.

// ---------------- prep: pack x, W_QKV, W_O fragment-major --------------------
__global__ __launch_bounds__(256) void prep_kernel(
    const float* __restrict__ x,  const float* __restrict__ Wq,
    const float* __restrict__ Wk, const float* __restrict__ Wv,
    const float* __restrict__ Wo,
    bf16* __restrict__ xp,  bf16* __restrict__ WTp, bf16* __restrict__ WoTp)
{
    const int tid = blockIdx.x * 256 + threadIdx.x;
    const int nth = gridDim.x * 256;

    // x [16384][768] f32 -> packed bf16
    for (int c = tid; c < BS*E_/8; c += nth) {
        const int r  = c / 96;               // row
        const int k8 = (c - r*96) * 8;       // k start (multiple of 8)
        const float4 f0 = *reinterpret_cast<const float4*>(x + (size_t)r*E_ + k8);
        const float4 f1 = *reinterpret_cast<const float4*>(x + (size_t)r*E_ + k8 + 4);
        union { bf16x8 v; __hip_bfloat162 h[4]; } u;
        u.h[0] = __float22bfloat162_rn(make_float2(f0.x, f0.y));
        u.h[1] = __float22bfloat162_rn(make_float2(f0.z, f0.w));
        u.h[2] = __float22bfloat162_rn(make_float2(f1.x, f1.y));
        u.h[3] = __float22bfloat162_rn(make_float2(f1.z, f1.w));
        const size_t dst = (size_t)((r>>4)*24 + (k8>>5))*512
                         + (size_t)((((k8>>3)&3)<<4) + (r&15))*8;
        *reinterpret_cast<bf16x8*>(xp + dst) = u.v;
    }

    // W_{Q,K,V}[n][e][h] -> packed B rows r = mat*768 + (n*64+h), k = e
    for (int c2 = tid; c2 < NHD*96; c2 += nth) {
        const int r  = c2 / 96;              // (n,h) output-col index 0..767
        const int e8 = (c2 - r*96) * 8;      // k start
        const int n = r >> 6, h = r & 63;
        const float* sq = Wq + (size_t)(n*E_ + e8)*HD + h;
        const float* sk = Wk + (size_t)(n*E_ + e8)*HD + h;
        const float* sv = Wv + (size_t)(n*E_ + e8)*HD + h;
        union { bf16x8 v; bf16 el[8]; } uq, uk, uv;
        #pragma unroll
        for (int j = 0; j < 8; ++j) {
            uq.el[j] = __float2bfloat16(sq[(size_t)j*HD]);
            uk.el[j] = __float2bfloat16(sk[(size_t)j*HD]);
            uv.el[j] = __float2bfloat16(sv[(size_t)j*HD]);
        }
        const size_t sub = (size_t)(e8>>5)*512
                         + (size_t)((((e8>>3)&3)<<4) + (r&15))*8;
        const size_t rg  = (size_t)(r>>4);   // within-matrix row-group
        *reinterpret_cast<bf16x8*>(WTp + ((0*48 + rg)*24)*512 + sub) = uq.v;
        *reinterpret_cast<bf16x8*>(WTp + ((1*48 + rg)*24)*512 + sub) = uk.v;
        *reinterpret_cast<bf16x8*>(WTp + ((2*48 + rg)*24)*512 + sub) = uv.v;
    }

    // Wo flat[c][e] -> packed B^T rows e (0..767), k = c (0..767)
    for (int c3 = tid; c3 < E_*96; c3 += nth) {
        const int e  = c3 / 96;
        const int c8 = (c3 - e*96) * 8;
        union { bf16x8 v; bf16 el[8]; } u;
        #pragma unroll
        for (int j = 0; j < 8; ++j)
            u.el[j] = __float2bfloat16(Wo[(size_t)(c8 + j)*E_ + e]);
        const size_t dst = (size_t)((e>>4)*24 + (c8>>5))*512
                         + (size_t)((((c8>>3)&3)<<4) + (e&15))*8;
        *reinterpret_cast<bf16x8*>(WoTp + dst) = u.v;
    }
}

// ========== direct packed GEMM, explicit 2-deep prefetch pipeline ============
// Per body: issue next-K-tile loads into the dead operand set, sched_barrier(0)
// (pins loads above the MFMA cluster -> the auto-waitcnt for the live set
// becomes a counted vmcnt with a full K-tile of lead), then the MFMA cluster.
// No LDS, no barriers: waves free-run, 2 waves/SIMD interleave for extra cover.

#define LOAD_A(dst, base, kt, NM)                                                 \
    _Pragma("unroll") for (int m = 0; m < NM; ++m)                                \
    _Pragma("unroll") for (int ks = 0; ks < 2; ++ks)                              \
        dst[m][ks] = ld8((base) + ((size_t)m*24 + (kt)*2 + ks)*512);

#define MFMA_BLK(af, bfv, NM, NN)                                                 \
    _Pragma("unroll") for (int ks = 0; ks < 2; ++ks)                              \
    _Pragma("unroll") for (int m = 0; m < NM; ++m)                                \
    _Pragma("unroll") for (int n = 0; n < NN; ++n)                                \
        acc[m][n] = mfma16(af[m][ks], bfv[n][ks], acc[m][n]);

#define DIRECT_PIPE_BODY(Abase, Bbase, NM, NN)                                    \
    f32x4 acc[NM][NN];                                                            \
    _Pragma("unroll") for (int mf = 0; mf < NM; ++mf)                             \
    _Pragma("unroll") for (int nf = 0; nf < NN; ++nf)                             \
        acc[mf][nf] = (f32x4){0.f, 0.f, 0.f, 0.f};                                \
    bf16x8 a0[NM][2], b0[NN][2], a1[NM][2], b1[NN][2];                            \
    LOAD_A(a0, Abase, 0, NM); LOAD_A(b0, Bbase, 0, NN);                           \
    _Pragma("unroll 1")                                                           \
    for (int kk = 0; kk < 6; ++kk) {                                              \
        const int ktA = 2*kk + 1;                                                 \
        const int ktB = (2*kk + 2 < 12) ? 2*kk + 2 : 11;                          \
        LOAD_A(a1, Abase, ktA, NM); LOAD_A(b1, Bbase, ktA, NN);                   \
        __builtin_amdgcn_sched_barrier(0);                                        \
        MFMA_BLK(a0, b0, NM, NN);                                                 \
        LOAD_A(a0, Abase, ktB, NM); LOAD_A(b0, Bbase, ktB, NN);                   \
        __builtin_amdgcn_sched_barrier(0);                                        \
        MFMA_BLK(a1, b1, NM, NN);                                                 \
    }

// ---------------- QKV projection: 128x128 blocks, wave tile 64x64 ------------
// WTp = packed [Wq;Wk;Wv] B-frags (144 row-groups); tn 0..17 spans it.
__global__ __launch_bounds__(256, 2) void qkv_gemm_p(
    const bf16* __restrict__ xp, const bf16* __restrict__ WTp,
    const float* __restrict__ bq, const float* __restrict__ bk, const float* __restrict__ bv,
    bf16* __restrict__ Qb, bf16* __restrict__ Kb, bf16* __restrict__ VTb)
{
    const int tm = blockIdx.x, tn = blockIdx.y;   // (128, 18)
    const int lane = threadIdx.x & 63;
    const int w    = threadIdx.x >> 6;            // 0..3
    const int wm = w >> 1, wn = w & 1;
    const int l16 = lane & 15, quad = lane >> 4;
    const bf16* Abase = xp  + ((size_t)(tm*8 + wm*4)*24)*512 + lane*8;
    const bf16* Bbase = WTp + ((size_t)(tn*8 + wn*4)*24)*512 + lane*8;

    DIRECT_PIPE_BODY(Abase, Bbase, 4, 4);

    const int mat = tn / 6;                  // 0=Q 1=K 2=V
    const int cloc0 = (tn - mat*6)*128 + wn*64;
    const float* bias = (mat==0) ? bq : (mat==1) ? bk : bv;
    const float scale = (mat==0) ? 0.125f * 1.44269504088896340736f : 1.0f;
    bf16* dstQK = (mat==0) ? Qb : Kb;
    #pragma unroll
    for (int nf = 0; nf < 4; ++nf) {
        const int col = cloc0 + nf*16 + l16;       // 0..767 within matrix
        const int hn = col >> 6, h = col & 63;
        const float bb = bias[col];
        #pragma unroll
        for (int mf = 0; mf < 4; ++mf) {
            const int row = tm*128 + wm*64 + mf*16 + quad*4;
            const int bi = row >> 11;              // / S_
            const int s  = row & (S_-1);
            if (mat < 2) {                         // Q,K -> [B][N][S][H]
                bf16* d = dstQK + ((size_t)(bi*NHEADS + hn)*S_ + s)*HD + h;
                #pragma unroll
                for (int r = 0; r < 4; ++r)
                    d[(size_t)r*HD] = __float2bfloat16((acc[mf][nf][r] + bb)*scale);
            } else {                               // V -> transposed [B][N][H][S]
                bf16* d = VTb + ((size_t)(bi*NHEADS + hn)*HD + h)*S_ + s;
                union { bf16x4 v; bf16 e[4]; } u;
                #pragma unroll
                for (int r = 0; r < 4; ++r) u.e[r] = __float2bfloat16(acc[mf][nf][r] + bb);
                *reinterpret_cast<bf16x4*>(d) = u.v;   // s%4==0 -> 8B aligned
            }
        }
    }
}

// ---------------- output projection: 128x96 blocks, wave tile 64x48 ----------
// A = Zp (fragment-major, written by attn), B = WoTp. Grid (128, 8) = exactly
// 2 dispatch rounds at 2 blocks/CU.
__global__ __launch_bounds__(256, 2) void out_gemm_p(
    const bf16* __restrict__ Zp, const bf16* __restrict__ WoTp,
    const float* __restrict__ bo, float* __restrict__ out)
{
    const int tm = blockIdx.x, tn = blockIdx.y;   // (128, 8)
    const int lane = threadIdx.x & 63;
    const int w    = threadIdx.x >> 6;
    const int wm = w >> 1, wn = w & 1;
    const int l16 = lane & 15, quad = lane >> 4;
    const bf16* Abase = Zp   + ((size_t)(tm*8 + wm*4)*24)*512 + lane*8;
    const bf16* Bbase = WoTp + ((size_t)(tn*6 + wn*3)*24)*512 + lane*8;

    DIRECT_PIPE_BODY(Abase, Bbase, 4, 3);

    #pragma unroll
    for (int nf = 0; nf < 3; ++nf) {
        const int col = tn*96 + wn*48 + nf*16 + l16;
        const float bb = bo[col];
        #pragma unroll
        for (int mf = 0; mf < 4; ++mf) {
            const int row = tm*128 + wm*64 + mf*16 + quad*4;
            float* d = out + (size_t)row*E_ + col;
            #pragma unroll
            for (int r = 0; r < 4; ++r)
                d[(size_t)r*E_] = acc[mf][nf][r] + bb;
        }
    }
}

// ---------------- flash attention (LDS-staged K/V, double-buffered) -----------
// Unchanged except: Z is written directly in fragment-major (Zp) so out_gemm
// reads contiguous 1KB wave-loads.
__global__ __launch_bounds__(256, 3) void attn_kernel(
    const bf16* __restrict__ Qb, const bf16* __restrict__ Kb,
    const bf16* __restrict__ VTb, bf16* __restrict__ Zp)
{
    __shared__ __align__(16) bf16 sK[2][64*64];
    __shared__ __align__(16) bf16 sV[2][64*64];

    const int id = blockIdx.x;
    const int bx = id / 96;                  // 0..7
    const int g  = id - bx*96;
    const int hn = g % NHEADS, b = g / NHEADS;
    const int tid  = threadIdx.x;
    const int w    = tid >> 6;
    const int lane = tid & 63;
    const int l16 = lane & 15, quad = lane >> 4;
    const size_t bn = (size_t)b*NHEADS + hn;

    const bf16* Qbase = Qb  + bn*S_*HD;
    const bf16* Kbase = Kb  + bn*S_*HD;
    const bf16* Vbase = VTb + bn*HD*S_;

    const int mA = tid, mB = tid + 256;
    const int rA = mA >> 3, cgA = mA & 7;
    const int rB = mB >> 3, cgB = mB & 7;
    const int slA = (rA*8 + ((cgA + rA + (rA>>3)) & 7)) * 8;
    const int slB = (rB*8 + ((cgB + rB + (rB>>3)) & 7)) * 8;
    const size_t vofA = (size_t)rA*S_ + cgA*8;
    const size_t vofB = (size_t)rB*S_ + cgB*8;

    const int kperm = (l16 >> 2)*8 + (l16 & 3);
    int kidx[2][2][2];
    #pragma unroll
    for (int c=0;c<2;c++)
        #pragma unroll
        for (int bg=0;bg<2;bg++)
            #pragma unroll
            for (int hf=0;hf<2;hf++) {
                const int r = 32*c + 4*bg + kperm;
                const int q = hf*4 + quad;
                kidx[c][bg][hf] = (r*8 + ((q + r + (r>>3)) & 7)) * 8;
            }
    int vidx[4][2];
    #pragma unroll
    for (int ht=0;ht<4;ht++)
        #pragma unroll
        for (int c=0;c<2;c++) {
            const int rho = ht*16 + l16;
            const int q = c*4 + quad;
            vidx[ht][c] = (rho*8 + ((q + rho + (rho>>3)) & 7)) * 8;
        }

    #pragma unroll
    for (int half = 0; half < 2; ++half) {
        const int qblk = half ? (S_/128 - 1 - bx) : bx;
        const int ktb  = 2*qblk + 1;
        const int ktw  = 2*qblk + (w >> 1);
        const int qbase = qblk*128 + w*32;

        bf16x8 bqf[2][2];
        #pragma unroll
        for (int qi=0;qi<2;qi++)
            #pragma unroll
            for (int hf=0;hf<2;hf++)
                bqf[qi][hf] = ld8(Qbase + (size_t)(qbase + qi*16 + l16)*HD + hf*32 + quad*8);

        f32x4 acc[2][4];
        #pragma unroll
        for (int qi=0;qi<2;qi++)
            #pragma unroll
            for (int ht=0;ht<4;ht++) acc[qi][ht] = (f32x4){0.f,0.f,0.f,0.f};
        float lsum[2] = {0.f, 0.f};

        bf16x8 k0 = ld8(Kbase + (size_t)mA*8);
        bf16x8 k1 = ld8(Kbase + (size_t)mB*8);
        bf16x8 v0 = ld8(Vbase + vofA);
        bf16x8 v1 = ld8(Vbase + vofB);
        *reinterpret_cast<bf16x8*>(&sK[0][slA]) = k0;
        *reinterpret_cast<bf16x8*>(&sK[0][slB]) = k1;
        *reinterpret_cast<bf16x8*>(&sV[0][slA]) = v0;
        *reinterpret_cast<bf16x8*>(&sV[0][slB]) = v1;
        __syncthreads();

        for (int kt = 0; kt <= ktb; ++kt) {
            if (kt < ktb) {
                const size_t kt1 = (size_t)(kt+1)*64;
                k0 = ld8(Kbase + kt1*HD + (size_t)mA*8);
                k1 = ld8(Kbase + kt1*HD + (size_t)mB*8);
                v0 = ld8(Vbase + vofA + kt1);
                v1 = ld8(Vbase + vofB + kt1);
            }
            if (kt <= ktw) {
                const bf16* kb = sK[kt & 1];
                const bf16* vb = sV[kt & 1];
                #pragma unroll
                for (int c=0;c<2;c++) {
                    const bf16x8 akA0 = ld8(kb + kidx[c][0][0]);
                    const bf16x8 akA1 = ld8(kb + kidx[c][0][1]);
                    const bf16x8 akB0 = ld8(kb + kidx[c][1][0]);
                    const bf16x8 akB1 = ld8(kb + kidx[c][1][1]);
                    bf16x8 av[4];
                    #pragma unroll
                    for (int ht=0;ht<4;ht++) av[ht] = ld8(vb + vidx[ht][c]);

                    #pragma unroll
                    for (int qi=0;qi<2;qi++) {
                        f32x4 s0 = (f32x4){0.f,0.f,0.f,0.f};
                        s0 = mfma16(akA0, bqf[qi][0], s0);
                        s0 = mfma16(akA1, bqf[qi][1], s0);
                        f32x4 s1 = (f32x4){0.f,0.f,0.f,0.f};
                        s1 = mfma16(akB0, bqf[qi][0], s1);
                        s1 = mfma16(akB1, bqf[qi][1], s1);
                        if (kt == ktw) {
                            const int q  = qbase + qi*16 + l16;
                            const int kb0 = kt*64 + c*32 + quad*8;
                            #pragma unroll
                            for (int r=0;r<4;r++) {
                                s0[r] = (kb0 + r     > q) ? -1e30f : s0[r];
                                s1[r] = (kb0 + 4 + r > q) ? -1e30f : s1[r];
                            }
                        }
                        float ls = 0.f;
                        #pragma unroll
                        for (int r=0;r<4;r++) {
                            s0[r] = __builtin_amdgcn_exp2f(s0[r]);
                            s1[r] = __builtin_amdgcn_exp2f(s1[r]);
                            ls += s0[r] + s1[r];
                        }
                        lsum[qi] += ls;
                        const bf16x8 pf = pack8(s0, s1);
                        #pragma unroll
                        for (int ht=0;ht<4;ht++)
                            acc[qi][ht] = mfma16(av[ht], pf, acc[qi][ht]);
                    }
                }
            }
            if (kt < ktb) {
                const int nb = (kt+1) & 1;
                *reinterpret_cast<bf16x8*>(&sK[nb][slA]) = k0;
                *reinterpret_cast<bf16x8*>(&sK[nb][slB]) = k1;
                *reinterpret_cast<bf16x8*>(&sV[nb][slA]) = v0;
                *reinterpret_cast<bf16x8*>(&sV[nb][slB]) = v1;
            }
            __syncthreads();
        }

        #pragma unroll
        for (int qi=0;qi<2;qi++) {
            float rs = lsum[qi];
            rs += __shfl_xor(rs, 16, 64);
            rs += __shfl_xor(rs, 32, 64);
            const float inv_l = 1.0f / rs;
            // fragment-major Z write: row = b*S_+q (row&15 == l16),
            // rowg = row>>4; k = hn*64 + ht*16 + quad*4 (4 contiguous elems)
            const int rowg = b*128 + (qbase >> 4) + qi;
            #pragma unroll
            for (int ht=0;ht<4;ht++) {
                union { bf16x4 v; bf16 e[4]; } u;
                #pragma unroll
                for (int r=0;r<4;r++) u.e[r] = __float2bfloat16(acc[qi][ht][r] * inv_l);
                const int k = hn*64 + ht*16 + quad*4;
                bf16* d = Zp + ((size_t)rowg*24 + (k>>5))*512
                             + (size_t)((((k>>3)&3)<<4) + l16)*8 + (k&7);
                *reinterpret_cast<bf16x4*>(d) = u.v;   // 8B aligned
            }
        }
    }
}

extern "C" void kernel_launch(void* const* d_in, const int* in_sizes, int n_in,
                              void* d_out, int out_size, void* d_ws, size_t ws_size,
                              hipStream_t stream)
{
    const float* x  = (const float*)d_in[0];
    const float* Wq = (const float*)d_in[1];
    const float* Wk = (const float*)d_in[2];
    const float* Wv = (const float*)d_in[3];
    const float* Wo = (const float*)d_in[4];
    const float* bq = (const float*)d_in[5];
    const float* bk = (const float*)d_in[6];
    const float* bv = (const float*)d_in[7];
    const float* bo = (const float*)d_in[8];
    float* out = (float*)d_out;

    char* ws = (char*)d_ws;
    size_t off = 0;
    auto alloc = [&](size_t bytes){ char* p = ws + off; off += (bytes + 255) & ~(size_t)255; return p; };
    bf16* xp   = (bf16*)alloc((size_t)BS*E_*2);     // packed fragment-major
    bf16* WTp  = (bf16*)alloc((size_t)3*NHD*E_*2);  // packed [Wq;Wk;Wv] B-frags
    bf16* WoTp = (bf16*)alloc((size_t)E_*NHD*2);    // packed Wo^T B-frags
    bf16* Qb   = (bf16*)alloc((size_t)BS*NHD*2);    // [B][N][S][H], pre-scaled log2e/8
    bf16* Kb   = (bf16*)alloc((size_t)BS*NHD*2);    // [B][N][S][H]
    bf16* VTb  = (bf16*)alloc((size_t)BS*NHD*2);    // [B][N][H][S]
    bf16* Zp   = (bf16*)alloc((size_t)BS*NHD*2);    // fragment-major Z

    prep_kernel<<<4096, 256, 0, stream>>>(x, Wq, Wk, Wv, Wo, xp, WTp, WoTp);
    qkv_gemm_p<<<dim3(BS/128, 18), 256, 0, stream>>>(xp, WTp, bq, bk, bv, Qb, Kb, VTb);
    attn_kernel<<<768, 256, 0, stream>>>(Qb, Kb, VTb, Zp);
    out_gemm_p<<<dim3(BS/128, 8), 256, 0, stream>>>(Zp, WoTp, bo, out);
}